// Round 7
// baseline (468.005 us; speedup 1.0000x reference)
//
#include <hip/hip_runtime.h>

// Sliding-window attention, MI355X/gfx950. Round 12.
// Pipeline: convert x->bf16, convert+transpose weights -> bf16;
// 256^2 phased MFMA GEMM (qkv, bf16 out) -> V transpose -> flash windowed
// attention (R10 counted-vmcnt pipeline, unchanged) -> 256^2 GEMM with FP32
// epilogue into d_out. ws usage: 200 MB.
//
// R6: don't feed MFMA from global. R8: forced waves/EU cap => spill.
// R9: gload_lds w=16 + pre-swizzled source. R10: counted-vmcnt + raw
// s_barrier pipeline (attn, verified). R11 LESSON: launch_bounds(512,2)
// caps the UNIFIED VGPR+AGPR file at 256; acc(128 AGPR)+bfr+afr+addrs
// exceeded it -> scratch spill (WRITE 185MB vs 115, MfmaUtil 28). LDS
// already limits to 1 block/CU, so the cap bought nothing.
// R12: (a) launch_bounds(512,1) - no reg cap, no spill, same occupancy;
// (b) A-staging spread across phases (quadrant-p rows are dead after
// phase p's barrier -> stage tile t+2's matching rows there); B staged
// after phase 3 as before. vmcnt(8)/vmcnt(0) boundary accounting unchanged
// (same 8 loads/tile/thread, same issue order constraints).

typedef unsigned short u16;
typedef unsigned int u32;
typedef __attribute__((ext_vector_type(8))) short bf16x8;   // 8 x bf16 (4 VGPRs)
typedef __attribute__((ext_vector_type(4))) float f32x4;

__device__ __forceinline__ float bf2f(u16 v) {
  union { u32 u; float f; } t; t.u = ((u32)v) << 16; return t.f;
}
__device__ __forceinline__ u16 f2bf(float f) {
  union { float f; u32 u; } t; t.f = f;
  u32 u = t.u + 0x7fffu + ((t.u >> 16) & 1u);   // RNE
  return (u16)(u >> 16);
}
__device__ __forceinline__ void g2lds16(const void* g, void* l) {
  __builtin_amdgcn_global_load_lds((const __attribute__((address_space(1))) void*)g,
                                   (__attribute__((address_space(3))) void*)l,
                                   16, 0, 0);
}

// ---------------------------------------------------------------------------
// x [16384][1024] fp32 -> bf16, flat
// ---------------------------------------------------------------------------
__global__ __launch_bounds__(256) void canon_x(
    const float* __restrict__ xf, u16* __restrict__ xb) {
  size_t i = ((size_t)blockIdx.x * 256 + threadIdx.x) * 8;
  float4 a = *(const float4*)(xf + i);
  float4 b = *(const float4*)(xf + i + 4);
  u16 o[8] = { f2bf(a.x), f2bf(a.y), f2bf(a.z), f2bf(a.w),
               f2bf(b.x), f2bf(b.y), f2bf(b.z), f2bf(b.w) };
  *(bf16x8*)(xb + i) = *(bf16x8*)o;
}

// ---------------------------------------------------------------------------
// Weight transpose+convert: in [R][C] fp32 -> out [C][R] bf16
// ---------------------------------------------------------------------------
__global__ __launch_bounds__(256) void transpose_w(
    const float* __restrict__ in, u16* __restrict__ out, int R, int C) {
  __shared__ u16 tile[32][33];
  int c0 = blockIdx.x * 32, r0 = blockIdx.y * 32;
  int tx = threadIdx.x & 31, ty = threadIdx.x >> 5;
#pragma unroll
  for (int i = 0; i < 32; i += 8)
    tile[ty + i][tx] = f2bf(in[(size_t)(r0 + ty + i) * C + c0 + tx]);
  __syncthreads();
#pragma unroll
  for (int i = 0; i < 32; i += 8)
    out[(size_t)(c0 + ty + i) * R + r0 + tx] = tile[tx][ty + i];
}

// ---------------------------------------------------------------------------
// V part of qkv [16384][3072] -> Vt [bh=512][d=64][t=512]   (bf16)
// ---------------------------------------------------------------------------
__global__ __launch_bounds__(256) void transpose_v(
    const u16* __restrict__ qkv, u16* __restrict__ vt) {
  __shared__ u16 tile[32][33];
  int bh = blockIdx.z, bn = bh >> 4, h = bh & 15;
  int t0 = blockIdx.x * 32, d0 = blockIdx.y * 32;
  int tx = threadIdx.x & 31, ty = threadIdx.x >> 5;
  const u16* src = qkv + (size_t)(bn * 512) * 3072 + 2048 + h * 64;
#pragma unroll
  for (int i = 0; i < 32; i += 8)
    tile[ty + i][tx] = src[(size_t)(t0 + ty + i) * 3072 + d0 + tx];
  __syncthreads();
  u16* dst = vt + ((size_t)bh * 64 + d0) * 512 + t0;
#pragma unroll
  for (int i = 0; i < 32; i += 8)
    dst[(size_t)(ty + i) * 512 + tx] = tile[tx][ty + i];
}

// ---------------------------------------------------------------------------
// C[M,N] = A[M,K](bf16) * Bt[N,K]^T(bf16) + bias[N](fp32); OutT u16|float.
// 256^2 template: BM=BN=256, BK=64, 512 threads (2x4 waves of 128x64).
// LDS 128KB dbuf; 16B slots XOR-swizzled slot^(row&7) via pre-swizzled
// global source (linear gload_lds dest). Per tile t:
//   vmcnt(8|0) -> s_barrier -> B-frags (8 rd, held for the tile)
//   -> 4 phases { A-frags (4 rd); setprio1; 16 MFMA; setprio0; s_barrier;
//                 stage A rows [p*32) of tile t+2 (1 load/thread) }
//   -> stage B of tile t+2 (4 loads/thread).
// launch_bounds(512,1): LDS already caps at 1 block/CU; no reg cap => no
// spill (R11 lesson). Requires grid.x*grid.y % 8 == 0 for T1 (768, 256: ok).
// ---------------------------------------------------------------------------
template <typename OutT>
__global__ __launch_bounds__(512, 1) void gemm_bt_bias(
    const u16* __restrict__ A, const u16* __restrict__ Bt,
    const float* __restrict__ bias, OutT* __restrict__ C,
    int M, int N, int K) {
  __shared__ __align__(16) u16 As[2][256 * 64];
  __shared__ __align__(16) u16 Bs[2][256 * 64];
  const int tid = threadIdx.x;
  const int wave = tid >> 6, lane = tid & 63;
  const int quad = lane >> 4, l16 = lane & 15;
  const int wr = wave >> 2, wc = wave & 3;        // 2 x 4 wave grid

  // T1: XCD-contiguous logical block mapping.
  const int nbx = gridDim.x;
  const int ntot = nbx * gridDim.y;
  const int flat = blockIdx.y * nbx + blockIdx.x;
  const int swz = (flat & 7) * (ntot >> 3) + (flat >> 3);
  const int m0 = (swz / nbx) * 256, n0 = (swz % nbx) * 256;

  // staging maps (all fill LDS[row][slot] = G[row][slot ^ (row&7)]):
  const int r8 = tid >> 3;                        // 0..63
  const int sgm = ((tid & 7) ^ (r8 & 7)) * 8;     // source swizzle (u16 units)
  const u16* gA = A + (size_t)(m0 + r8) * K + sgm;    // full-tile: +l*64*K +kt
  const u16* gB = Bt + (size_t)(n0 + r8) * K + sgm;
  const int rl = r8 & 31;
  const int halfsel = tid >> 8;                   // 0/1 (M-half)
  const u16* gAp = A + (size_t)(m0 + halfsel * 128 + rl) * K + sgm; // +p*32*K +kt
  const int ldsAp = halfsel * 8192 + (wave & 3) * 512 + lane * 8;   // +p*2048

#define STAGE_FULL(KT, BUF)                                                   \
  { _Pragma("unroll") for (int l = 0; l < 4; ++l) {                           \
      g2lds16(gA + (size_t)l * 64 * K + (KT),                                 \
              &As[BUF][((size_t)l * 512 + tid) * 8]);                         \
      g2lds16(gB + (size_t)l * 64 * K + (KT),                                 \
              &Bs[BUF][((size_t)l * 512 + tid) * 8]); } }
#define STAGE_A_PHASE(P, KT, BUF)                                             \
  g2lds16(gAp + (size_t)(P) * 32 * K + (KT), &As[BUF][ldsAp + (P) * 2048]);
#define STAGE_B_FULL(KT, BUF)                                                 \
  { _Pragma("unroll") for (int l = 0; l < 4; ++l)                             \
      g2lds16(gB + (size_t)l * 64 * K + (KT),                                 \
              &Bs[BUF][((size_t)l * 512 + tid) * 8]); }

  f32x4 acc[8][4] = {};
  const int NT = K >> 6;                          // 16 here

  STAGE_FULL(0, 0);
  STAGE_FULL(64, 1);

  for (int t = 0; t < NT; ++t) {
    // boundary: tile t landed; tile t+1's 8 loads stay in flight.
    if (t + 1 < NT) { asm volatile("s_waitcnt vmcnt(8)" ::: "memory"); }
    else            { asm volatile("s_waitcnt vmcnt(0)" ::: "memory"); }
    __builtin_amdgcn_s_barrier();
    __builtin_amdgcn_sched_barrier(0);

    const u16* Ab = &As[t & 1][0];
    const u16* Bb = &Bs[t & 1][0];
    const int kt2 = (t + 2) * 64;
    const int buf = t & 1;
    const bool st = (t + 2 < NT);

    // B-frags for the whole tile (held: 32 VGPR; LDS roofline requires it)
    bf16x8 bfr[2][4];                             // [ks][ni]
#pragma unroll
    for (int ks = 0; ks < 2; ++ks)
#pragma unroll
      for (int ni = 0; ni < 4; ++ni) {
        int row = wc * 64 + ni * 16 + l16;
        bfr[ks][ni] = *(const bf16x8*)(Bb + row * 64 + (((ks * 4 + quad) ^ (row & 7)) * 8));
      }

#pragma unroll
    for (int p = 0; p < 4; ++p) {
      bf16x8 afr[2][2];                           // [mm][ks] (transient)
#pragma unroll
      for (int mm = 0; mm < 2; ++mm)
#pragma unroll
        for (int ks = 0; ks < 2; ++ks) {
          int row = wr * 128 + (p * 2 + mm) * 16 + l16;
          afr[mm][ks] = *(const bf16x8*)(Ab + row * 64 + (((ks * 4 + quad) ^ (row & 7)) * 8));
        }
      __builtin_amdgcn_s_setprio(1);
#pragma unroll
      for (int mm = 0; mm < 2; ++mm)
#pragma unroll
        for (int ni = 0; ni < 4; ++ni)
#pragma unroll
          for (int ks = 0; ks < 2; ++ks)
            acc[p * 2 + mm][ni] = __builtin_amdgcn_mfma_f32_16x16x32_bf16(
                afr[mm][ks], bfr[ks][ni], acc[p * 2 + mm][ni], 0, 0, 0);
      __builtin_amdgcn_s_setprio(0);
      __builtin_amdgcn_s_barrier();               // quadrant-p A rows now free
      __builtin_amdgcn_sched_barrier(0);
      if (st) { STAGE_A_PHASE(p, kt2, buf); }     // refill freed A rows, t+2
    }
    if (st) { STAGE_B_FULL(kt2, buf); }           // B free after phase 3
  }
#undef STAGE_FULL
#undef STAGE_A_PHASE
#undef STAGE_B_FULL

  // epilogue: C/D layout col=l16, row=quad*4+reg  (R11-verified)
#pragma unroll
  for (int ni = 0; ni < 4; ++ni) {
    int col = n0 + wc * 64 + ni * 16 + l16;
    float bv = bias[col];
#pragma unroll
    for (int mi = 0; mi < 8; ++mi) {
      int row0 = m0 + wr * 128 + mi * 16 + quad * 4;
#pragma unroll
      for (int r = 0; r < 4; ++r) {
        float v = acc[mi][ni][r] + bv;
        if constexpr (sizeof(OutT) == 2)
          C[(size_t)(row0 + r) * N + col] = f2bf(v);
        else
          C[(size_t)(row0 + r) * N + col] = v;
      }
    }
  }
}

// ---------------------------------------------------------------------------
// Windowed causal flash attention. Grid (qt=4, h=16, bn=32), 256 threads.
// R10 (verified): counted-vmcnt pipeline, raw s_barrier, no __syncthreads.
// UNCHANGED.
// ---------------------------------------------------------------------------
__global__ __launch_bounds__(256, 2) void attn_win(
    const u16* __restrict__ qkv, const u16* __restrict__ vt,
    u16* __restrict__ attn) {
  __shared__ __align__(16) u16 Ks[128 * 64];
  __shared__ __align__(16) u16 Vs[64 * 128];
  __shared__ __align__(16) u16 Ps[4][16 * 128];

  const int qt = blockIdx.x, h = blockIdx.y, bn = blockIdx.z;
  const int bh = bn * 16 + h;
  const int tid = threadIdx.x;
  const int wave = tid >> 6, lane = tid & 63;
  const int quad = lane >> 4, l16 = lane & 15;
  const int t0 = bn * 512 + qt * 128;

  bf16x8 aq[2][2];
#pragma unroll
  for (int mi = 0; mi < 2; ++mi)
#pragma unroll
    for (int ks = 0; ks < 2; ++ks)
      aq[mi][ks] = *(const bf16x8*)(
          qkv + (size_t)(t0 + wave * 32 + mi * 16 + l16) * 3072 + h * 64 + ks * 32 + quad * 8);

  const int rk0 = tid >> 3, ck0 = tid & 7;
  const int rv0 = tid >> 4, cv0 = tid & 15;

#define STAGE_K(JT)                                                           \
  {                                                                           \
    const int tk_ = bn * 512 + (JT) * 128;                                    \
    _Pragma("unroll")                                                         \
    for (int it = 0; it < 4; ++it) {                                          \
      int rk = it * 32 + rk0;                                                 \
      const u16* gk = qkv + (size_t)(tk_ + rk) * 3072 + 1024 + h * 64 +       \
                      ((ck0 ^ (rk & 7)) * 8);                                 \
      g2lds16(gk, Ks + (size_t)(it * 256 + wave * 64) * 8);                   \
    }                                                                         \
  }
#define STAGE_V(JT)                                                           \
  {                                                                           \
    _Pragma("unroll")                                                         \
    for (int it = 0; it < 4; ++it) {                                          \
      int rv = it * 16 + rv0;                                                 \
      const u16* gv = vt + ((size_t)bh * 64 + rv) * 512 + (JT) * 128 +        \
                      ((cv0 ^ (rv & 15)) * 8);                                \
      g2lds16(gv, Vs + (size_t)(it * 256 + wave * 64) * 8);                   \
    }                                                                         \
  }

  STAGE_K(0);
  STAGE_V(0);
  asm volatile("s_waitcnt vmcnt(4)" ::: "memory");
  __builtin_amdgcn_s_barrier();
  __builtin_amdgcn_sched_barrier(0);

  float mrun[2][4], lrun[2][4];
  f32x4 o[2][4] = {};
#pragma unroll
  for (int mi = 0; mi < 2; ++mi)
#pragma unroll
    for (int r = 0; r < 4; ++r) { mrun[mi][r] = -1e30f; lrun[mi][r] = 0.f; }

  const float cexp = 0.18033688011112042f;  // (1/sqrt(64)) * log2(e)

  u16* pw = &Ps[wave][0];

  for (int j = 0; j <= qt; ++j) {
    f32x4 s[2][8] = {};
    __builtin_amdgcn_s_setprio(1);
#pragma unroll
    for (int ks = 0; ks < 2; ++ks) {
#pragma unroll
      for (int ni = 0; ni < 8; ++ni) {
        int n = ni * 16 + l16;
        bf16x8 bk = *(const bf16x8*)(Ks + n * 64 + (((ks * 4 + quad) ^ (n & 7)) * 8));
        s[0][ni] = __builtin_amdgcn_mfma_f32_16x16x32_bf16(aq[0][ks], bk, s[0][ni], 0, 0, 0);
        s[1][ni] = __builtin_amdgcn_mfma_f32_16x16x32_bf16(aq[1][ks], bk, s[1][ni], 0, 0, 0);
      }
    }
    __builtin_amdgcn_s_setprio(0);

    __builtin_amdgcn_s_barrier();
    __builtin_amdgcn_sched_barrier(0);
    if (j < qt) STAGE_K(j + 1);

    const bool diag = (j == qt);
#pragma unroll
    for (int mi = 0; mi < 2; ++mi) {
#pragma unroll
      for (int r = 0; r < 4; ++r) {
        int m = wave * 32 + mi * 16 + quad * 4 + r;
        float rmax = -1e30f;
#pragma unroll
        for (int ni = 0; ni < 8; ++ni) {
          float v = s[mi][ni][r] * cexp;
          if (diag && (ni * 16 + l16 > m)) v = -1e30f;
          s[mi][ni][r] = v;
          rmax = fmaxf(rmax, v);
        }
        rmax = fmaxf(rmax, __shfl_xor(rmax, 1));
        rmax = fmaxf(rmax, __shfl_xor(rmax, 2));
        rmax = fmaxf(rmax, __shfl_xor(rmax, 4));
        rmax = fmaxf(rmax, __shfl_xor(rmax, 8));
        float mnew = fmaxf(mrun[mi][r], rmax);
        float alpha = exp2f(mrun[mi][r] - mnew);
        mrun[mi][r] = mnew;
        float rsum = 0.f;
#pragma unroll
        for (int ni = 0; ni < 8; ++ni) {
          float pv = exp2f(s[mi][ni][r] - mnew);
          s[mi][ni][r] = pv;
          rsum += pv;
        }
        rsum += __shfl_xor(rsum, 1);
        rsum += __shfl_xor(rsum, 2);
        rsum += __shfl_xor(rsum, 4);
        rsum += __shfl_xor(rsum, 8);
        lrun[mi][r] = lrun[mi][r] * alpha + rsum;
#pragma unroll
        for (int di = 0; di < 4; ++di) o[mi][di][r] *= alpha;
      }
    }

    if (j < qt) { asm volatile("s_waitcnt vmcnt(4)" ::: "memory"); }
    else        { asm volatile("s_waitcnt vmcnt(0)" ::: "memory"); }
    __builtin_amdgcn_s_barrier();
    __builtin_amdgcn_sched_barrier(0);

#pragma unroll
    for (int mi = 0; mi < 2; ++mi) {
#pragma unroll
      for (int ni = 0; ni < 8; ++ni)
#pragma unroll
        for (int r = 0; r < 4; ++r) {
          int row = quad * 4 + r;
          int col = ni * 16 + l16;
          int phys = (col >> 3) ^ row;
          pw[row * 128 + phys * 8 + (col & 7)] = f2bf(s[mi][ni][r]);
        }

      __builtin_amdgcn_s_setprio(1);
#pragma unroll
      for (int ksv = 0; ksv < 4; ++ksv) {
        bf16x8 ap = *(const bf16x8*)(pw + l16 * 128 + (((ksv * 4 + quad) ^ l16) * 8));
#pragma unroll
        for (int di = 0; di < 4; ++di) {
          int n = di * 16 + l16;
          bf16x8 bv = *(const bf16x8*)(Vs + n * 128 + (((ksv * 4 + quad) ^ (n & 15)) * 8));
          o[mi][di] = __builtin_amdgcn_mfma_f32_16x16x32_bf16(ap, bv, o[mi][di], 0, 0, 0);
        }
      }
      __builtin_amdgcn_s_setprio(0);
    }

    asm volatile("s_waitcnt vmcnt(0)" ::: "memory");
    __builtin_amdgcn_s_barrier();
    __builtin_amdgcn_sched_barrier(0);
    if (j < qt) STAGE_V(j + 1);
  }
#undef STAGE_K
#undef STAGE_V

#pragma unroll
  for (int mi = 0; mi < 2; ++mi)
#pragma unroll
    for (int r = 0; r < 4; ++r) {
      float inv = 1.0f / lrun[mi][r];
      int trow = t0 + wave * 32 + mi * 16 + quad * 4 + r;
#pragma unroll
      for (int di = 0; di < 4; ++di)
        attn[(size_t)trow * 1024 + h * 64 + di * 16 + l16] = f2bf(o[mi][di][r] * inv);
    }
}

// ---------------------------------------------------------------------------
extern "C" void kernel_launch(void* const* d_in, const int* in_sizes, int n_in,
                              void* d_out, int out_size, void* d_ws, size_t ws_size,
                              hipStream_t stream) {
  (void)in_sizes; (void)n_in; (void)out_size; (void)ws_size;
  const float* x     = (const float*)d_in[0];   // [16384][1024] fp32
  const float* w_qkv = (const float*)d_in[1];   // [1024][3072] fp32
  const float* b_qkv = (const float*)d_in[2];   // [3072] fp32
  const float* w_o   = (const float*)d_in[3];   // [1024][1024] fp32
  const float* b_o   = (const float*)d_in[4];   // [1024] fp32
  float* out = (float*)d_out;                   // [16384][1024] fp32

  char* ws = (char*)d_ws;
  u16* qkv   = (u16*)(ws + 0);            // 96 MB
  u16* vtb   = (u16*)(ws + 100663296);    // 32 MB
  u16* attnb = (u16*)(ws + 134217728);    // 32 MB
  u16* xb    = (u16*)(ws + 167772160);    // 32 MB
  u16* wqkvT = (u16*)(ws + 201326592);    // 6 MB
  u16* woT   = (u16*)(ws + 207618048);    // 2 MB  (total 200 MB)

  canon_x<<<8192, 256, 0, stream>>>(x, xb);
  transpose_w<<<dim3(96, 32), 256, 0, stream>>>(w_qkv, wqkvT, 1024, 3072);
  transpose_w<<<dim3(32, 32), 256, 0, stream>>>(w_o, woT, 1024, 1024);

  gemm_bt_bias<u16><<<dim3(12, 64), 512, 0, stream>>>(
      xb, wqkvT, b_qkv, qkv, 16384, 3072, 1024);
  transpose_v<<<dim3(16, 2, 512), 256, 0, stream>>>(qkv, vtb);
  attn_win<<<dim3(4, 16, 32), 256, 0, stream>>>(qkv, vtb, attnb);
  gemm_bt_bias<float><<<dim3(4, 64), 512, 0, stream>>>(
      attnb, woT, b_o, out, 16384, 1024, 1024);
}

// Round 9
// 434.272 us; speedup vs baseline: 1.0777x; 1.0777x over previous
//
#include <hip/hip_runtime.h>

// Sliding-window attention, MI355X/gfx950. Round 14 (= R13 resubmit; R8's
// bench was an infra "container failed twice", same signature as R2 which
// passed on resubmission; R13 re-audited: uniform barriers, verified vmcnt
// accounting, WAR-safe staging, ~200 reg peak < 256 -> no hang mechanism).
//
// Pipeline: convert x->bf16, convert+transpose weights -> bf16;
// 256^2 8-phase MFMA GEMM (qkv, bf16 out) -> V transpose -> flash windowed
// attention (R10 counted-vmcnt pipeline, unchanged) -> same GEMM with FP32
// epilogue into d_out. ws usage: 200 MB.
//
// R11/R12 LESSON: 512-thread blocks are ALWAYS 2 waves/SIMD => 256-reg cap;
// acc(128)+bfr(32)+afr(16)+addressing hit it => spill (WRITE +73MB) and my
// 2-deep schedule lacked m201's phase discipline (27.5% MfmaUtil vs 62%).
// R13/R14: faithful m201 8-phase port. Per iteration (2 K-tiles):
//   phase p: { ds-read A-quad (4 b128; +8 B on q==0) ; stage 1 half-tile
//              (2 gload_lds) ; pre-barrier ; lgkmcnt(0) ; setprio(1)
//              16 MFMA ; setprio(0) ; [vmcnt(4|0) at p==3,7] ; post-barrier }
// Half-tile schedule (WAR-safe, deadline-proven):
//   ph0/1: A(2i+1) -> buf1 (freed prev ph7; read ph4; landed by ph3 vmcnt(4))
//   ph2/3: B(2i+2) -> buf0 (freed ph0;     read next ph0; landed by ph7 vmcnt)
//   ph4/5: A(2i+2) -> buf0 (freed ph3;     read next ph0; landed by ph7 vmcnt)
//   ph6/7: B(2i+3) -> buf1 (freed ph4;     read next ph4; landed next ph3)
// Max 12 loads in flight; vmcnt(4) retires the 8 oldest = exactly what the
// next 4 phases read. Staging via R9-verified pre-swizzled source + linear
// gload_lds dest; readers use the same slot^(row&7) involution (T2).

typedef unsigned short u16;
typedef unsigned int u32;
typedef __attribute__((ext_vector_type(8))) short bf16x8;   // 8 x bf16 (4 VGPRs)
typedef __attribute__((ext_vector_type(4))) float f32x4;

__device__ __forceinline__ float bf2f(u16 v) {
  union { u32 u; float f; } t; t.u = ((u32)v) << 16; return t.f;
}
__device__ __forceinline__ u16 f2bf(float f) {
  union { float f; u32 u; } t; t.f = f;
  u32 u = t.u + 0x7fffu + ((t.u >> 16) & 1u);   // RNE
  return (u16)(u >> 16);
}
__device__ __forceinline__ void g2lds16(const void* g, void* l) {
  __builtin_amdgcn_global_load_lds((const __attribute__((address_space(1))) void*)g,
                                   (__attribute__((address_space(3))) void*)l,
                                   16, 0, 0);
}

// ---------------------------------------------------------------------------
// x [16384][1024] fp32 -> bf16, flat
// ---------------------------------------------------------------------------
__global__ __launch_bounds__(256) void canon_x(
    const float* __restrict__ xf, u16* __restrict__ xb) {
  size_t i = ((size_t)blockIdx.x * 256 + threadIdx.x) * 8;
  float4 a = *(const float4*)(xf + i);
  float4 b = *(const float4*)(xf + i + 4);
  u16 o[8] = { f2bf(a.x), f2bf(a.y), f2bf(a.z), f2bf(a.w),
               f2bf(b.x), f2bf(b.y), f2bf(b.z), f2bf(b.w) };
  *(bf16x8*)(xb + i) = *(bf16x8*)o;
}

// ---------------------------------------------------------------------------
// Weight transpose+convert: in [R][C] fp32 -> out [C][R] bf16
// ---------------------------------------------------------------------------
__global__ __launch_bounds__(256) void transpose_w(
    const float* __restrict__ in, u16* __restrict__ out, int R, int C) {
  __shared__ u16 tile[32][33];
  int c0 = blockIdx.x * 32, r0 = blockIdx.y * 32;
  int tx = threadIdx.x & 31, ty = threadIdx.x >> 5;
#pragma unroll
  for (int i = 0; i < 32; i += 8)
    tile[ty + i][tx] = f2bf(in[(size_t)(r0 + ty + i) * C + c0 + tx]);
  __syncthreads();
#pragma unroll
  for (int i = 0; i < 32; i += 8)
    out[(size_t)(c0 + ty + i) * R + r0 + tx] = tile[tx][ty + i];
}

// ---------------------------------------------------------------------------
// V part of qkv [16384][3072] -> Vt [bh=512][d=64][t=512]   (bf16)
// ---------------------------------------------------------------------------
__global__ __launch_bounds__(256) void transpose_v(
    const u16* __restrict__ qkv, u16* __restrict__ vt) {
  __shared__ u16 tile[32][33];
  int bh = blockIdx.z, bn = bh >> 4, h = bh & 15;
  int t0 = blockIdx.x * 32, d0 = blockIdx.y * 32;
  int tx = threadIdx.x & 31, ty = threadIdx.x >> 5;
  const u16* src = qkv + (size_t)(bn * 512) * 3072 + 2048 + h * 64;
#pragma unroll
  for (int i = 0; i < 32; i += 8)
    tile[ty + i][tx] = src[(size_t)(t0 + ty + i) * 3072 + d0 + tx];
  __syncthreads();
  u16* dst = vt + ((size_t)bh * 64 + d0) * 512 + t0;
#pragma unroll
  for (int i = 0; i < 32; i += 8)
    dst[(size_t)(ty + i) * 512 + tx] = tile[tx][ty + i];
}

// ---------------------------------------------------------------------------
// C[M,N] = A[M,K](bf16) * Bt[N,K]^T(bf16) + bias[N](fp32); OutT u16|float.
// 256^2 8-phase template (see header comment). 512 threads, 8 waves 2x4,
// per-wave 128x64 (acc[8][4]); LDS 128KB = As[2][2][128*64] + Bs same.
// ---------------------------------------------------------------------------
template <typename OutT>
__global__ __launch_bounds__(512) void gemm_bt_bias(
    const u16* __restrict__ A, const u16* __restrict__ Bt,
    const float* __restrict__ bias, OutT* __restrict__ C,
    int M, int N, int K) {
  __shared__ __align__(16) u16 As[2][2][128 * 64];   // [ktile-buf][M-half]
  __shared__ __align__(16) u16 Bs[2][2][128 * 64];   // [ktile-buf][N-half]
  const int tid = threadIdx.x;
  const int wave = tid >> 6, lane = tid & 63;
  const int quad = lane >> 4, l16 = lane & 15;
  const int wr = wave >> 2, wc = wave & 3;           // 2 x 4 wave grid

  // T1: XCD-contiguous logical block mapping (grid.x*grid.y % 8 == 0).
  const int nbx = gridDim.x;
  const int ntot = nbx * gridDim.y;
  const int flat = blockIdx.y * nbx + blockIdx.x;
  const int swz = (flat & 7) * (ntot >> 3) + (flat >> 3);
  const int m0 = (swz / nbx) * 256, n0 = (swz % nbx) * 256;

  // Half-tile staging (128x64 u16 = 16KB = 512 threads x 2 chunks x 16B).
  // Chunk c: row=c>>3, slot=c&7; linear LDS dest offset c*16B; source col
  // pre-swizzled (slot ^ (row&7)). (row+64)&7 == row&7, so one swizzle.
  const int rr = tid >> 3;                    // 0..63
  const int sc0 = ((tid & 7) ^ (rr & 7)) * 8; // source col offset (u16)

#define STAGE_HALF(SRC, DST, ROWBASE, KT)                                     \
  {                                                                           \
    g2lds16((SRC) + (size_t)((ROWBASE) + rr) * K + (KT) * 64 + sc0,           \
            (DST) + (size_t)tid * 8);                                         \
    g2lds16((SRC) + (size_t)((ROWBASE) + rr + 64) * K + (KT) * 64 + sc0,      \
            (DST) + (size_t)(tid + 512) * 8);                                 \
  }

  const int NT = K >> 6;                      // K-tiles of 64 (16 here)
  const int NI = NT >> 1;                     // iterations (2 K-tiles each)

  // prologue: A(0), B(0) fully; B(1) fully (A(1) arrives at ph0/1 of iter 0)
  STAGE_HALF(A,  &As[0][0][0], m0,       0);
  STAGE_HALF(A,  &As[0][1][0], m0 + 128, 0);
  STAGE_HALF(Bt, &Bs[0][0][0], n0,       0);
  STAGE_HALF(Bt, &Bs[0][1][0], n0 + 128, 0);
  STAGE_HALF(Bt, &Bs[1][0][0], n0,       1);
  STAGE_HALF(Bt, &Bs[1][1][0], n0 + 128, 1);
  asm volatile("s_waitcnt vmcnt(4)" ::: "memory");   // A(0),B(0) landed
  __builtin_amdgcn_s_barrier();
  __builtin_amdgcn_sched_barrier(0);

  f32x4 acc[8][4] = {};
  bf16x8 bfr[2][4];                           // B frags, held per K-tile

  for (int i = 0; i < NI; ++i) {
#pragma unroll
    for (int p = 0; p < 8; ++p) {
      const int tt = 2 * i + (p >> 2);        // current K-tile
      const int bb = tt & 1;
      const int q = p & 3;                    // quadrant within wave's 128 rows

      // ---- ds reads for this phase ----
      if (q == 0) {                           // B for the whole K-tile (8 rd)
        const u16* Bb = &Bs[bb][wc >> 1][0];
        const int rbase = (wc & 1) * 64;
#pragma unroll
        for (int ks = 0; ks < 2; ++ks)
#pragma unroll
          for (int ni = 0; ni < 4; ++ni) {
            int row = rbase + ni * 16 + l16;
            bfr[ks][ni] = *(const bf16x8*)(Bb + row * 64 + (((ks * 4 + quad) ^ (row & 7)) * 8));
          }
      }
      bf16x8 afr[2][2];                       // A quadrant (4 rd)
      {
        const u16* Ab = &As[bb][wr][0];
#pragma unroll
        for (int mm = 0; mm < 2; ++mm)
#pragma unroll
          for (int ks = 0; ks < 2; ++ks) {
            int row = q * 32 + mm * 16 + l16;
            afr[mm][ks] = *(const bf16x8*)(Ab + row * 64 + (((ks * 4 + quad) ^ (row & 7)) * 8));
          }
      }

      // ---- stage exactly 1 half-tile (schedule in header comment) ----
      switch (p) {
        case 0: if (2*i+1 < NT) STAGE_HALF(A,  &As[1][0][0], m0,       2*i+1); break;
        case 1: if (2*i+1 < NT) STAGE_HALF(A,  &As[1][1][0], m0 + 128, 2*i+1); break;
        case 2: if (2*i+2 < NT) STAGE_HALF(Bt, &Bs[0][0][0], n0,       2*i+2); break;
        case 3: if (2*i+2 < NT) STAGE_HALF(Bt, &Bs[0][1][0], n0 + 128, 2*i+2); break;
        case 4: if (2*i+2 < NT) STAGE_HALF(A,  &As[0][0][0], m0,       2*i+2); break;
        case 5: if (2*i+2 < NT) STAGE_HALF(A,  &As[0][1][0], m0 + 128, 2*i+2); break;
        case 6: if (2*i+3 < NT) STAGE_HALF(Bt, &Bs[1][0][0], n0,       2*i+3); break;
        case 7: if (2*i+3 < NT) STAGE_HALF(Bt, &Bs[1][1][0], n0 + 128, 2*i+3); break;
      }

      // ---- barrier; wait own ds reads; MFMA cluster ----
      __builtin_amdgcn_s_barrier();
      asm volatile("s_waitcnt lgkmcnt(0)" ::: "memory");
      __builtin_amdgcn_sched_barrier(0);
      __builtin_amdgcn_s_setprio(1);
#pragma unroll
      for (int mm = 0; mm < 2; ++mm)
#pragma unroll
        for (int ni = 0; ni < 4; ++ni)
#pragma unroll
          for (int ks = 0; ks < 2; ++ks)
            acc[q * 2 + mm][ni] = __builtin_amdgcn_mfma_f32_16x16x32_bf16(
                afr[mm][ks], bfr[ks][ni], acc[q * 2 + mm][ni], 0, 0, 0);
      __builtin_amdgcn_s_setprio(0);
      if (p == 3 || p == 7) {                 // counted vmcnt, once per K-tile
        if (i + 1 < NI) { asm volatile("s_waitcnt vmcnt(4)" ::: "memory"); }
        else            { asm volatile("s_waitcnt vmcnt(0)" ::: "memory"); }
      }
      __builtin_amdgcn_s_barrier();
      __builtin_amdgcn_sched_barrier(0);
    }
  }
#undef STAGE_HALF

  // epilogue: C/D layout col=l16, row=quad*4+reg  (R11-verified)
#pragma unroll
  for (int ni = 0; ni < 4; ++ni) {
    int col = n0 + wc * 64 + ni * 16 + l16;
    float bv = bias[col];
#pragma unroll
    for (int mi = 0; mi < 8; ++mi) {
      int row0 = m0 + wr * 128 + mi * 16 + quad * 4;
#pragma unroll
      for (int r = 0; r < 4; ++r) {
        float v = acc[mi][ni][r] + bv;
        if constexpr (sizeof(OutT) == 2)
          C[(size_t)(row0 + r) * N + col] = f2bf(v);
        else
          C[(size_t)(row0 + r) * N + col] = v;
      }
    }
  }
}

// ---------------------------------------------------------------------------
// Windowed causal flash attention. Grid (qt=4, h=16, bn=32), 256 threads.
// R10 (verified): counted-vmcnt pipeline, raw s_barrier, no __syncthreads.
// UNCHANGED.
// ---------------------------------------------------------------------------
__global__ __launch_bounds__(256, 2) void attn_win(
    const u16* __restrict__ qkv, const u16* __restrict__ vt,
    u16* __restrict__ attn) {
  __shared__ __align__(16) u16 Ks[128 * 64];
  __shared__ __align__(16) u16 Vs[64 * 128];
  __shared__ __align__(16) u16 Ps[4][16 * 128];

  const int qt = blockIdx.x, h = blockIdx.y, bn = blockIdx.z;
  const int bh = bn * 16 + h;
  const int tid = threadIdx.x;
  const int wave = tid >> 6, lane = tid & 63;
  const int quad = lane >> 4, l16 = lane & 15;
  const int t0 = bn * 512 + qt * 128;

  bf16x8 aq[2][2];
#pragma unroll
  for (int mi = 0; mi < 2; ++mi)
#pragma unroll
    for (int ks = 0; ks < 2; ++ks)
      aq[mi][ks] = *(const bf16x8*)(
          qkv + (size_t)(t0 + wave * 32 + mi * 16 + l16) * 3072 + h * 64 + ks * 32 + quad * 8);

  const int rk0 = tid >> 3, ck0 = tid & 7;
  const int rv0 = tid >> 4, cv0 = tid & 15;

#define STAGE_K(JT)                                                           \
  {                                                                           \
    const int tk_ = bn * 512 + (JT) * 128;                                    \
    _Pragma("unroll")                                                         \
    for (int it = 0; it < 4; ++it) {                                          \
      int rk = it * 32 + rk0;                                                 \
      const u16* gk = qkv + (size_t)(tk_ + rk) * 3072 + 1024 + h * 64 +       \
                      ((ck0 ^ (rk & 7)) * 8);                                 \
      g2lds16(gk, Ks + (size_t)(it * 256 + wave * 64) * 8);                   \
    }                                                                         \
  }
#define STAGE_V(JT)                                                           \
  {                                                                           \
    _Pragma("unroll")                                                         \
    for (int it = 0; it < 4; ++it) {                                          \
      int rv = it * 16 + rv0;                                                 \
      const u16* gv = vt + ((size_t)bh * 64 + rv) * 512 + (JT) * 128 +        \
                      ((cv0 ^ (rv & 15)) * 8);                                \
      g2lds16(gv, Vs + (size_t)(it * 256 + wave * 64) * 8);                   \
    }                                                                         \
  }

  STAGE_K(0);
  STAGE_V(0);
  asm volatile("s_waitcnt vmcnt(4)" ::: "memory");
  __builtin_amdgcn_s_barrier();
  __builtin_amdgcn_sched_barrier(0);

  float mrun[2][4], lrun[2][4];
  f32x4 o[2][4] = {};
#pragma unroll
  for (int mi = 0; mi < 2; ++mi)
#pragma unroll
    for (int r = 0; r < 4; ++r) { mrun[mi][r] = -1e30f; lrun[mi][r] = 0.f; }

  const float cexp = 0.18033688011112042f;  // (1/sqrt(64)) * log2(e)

  u16* pw = &Ps[wave][0];

  for (int j = 0; j <= qt; ++j) {
    f32x4 s[2][8] = {};
    __builtin_amdgcn_s_setprio(1);
#pragma unroll
    for (int ks = 0; ks < 2; ++ks) {
#pragma unroll
      for (int ni = 0; ni < 8; ++ni) {
        int n = ni * 16 + l16;
        bf16x8 bk = *(const bf16x8*)(Ks + n * 64 + (((ks * 4 + quad) ^ (n & 7)) * 8));
        s[0][ni] = __builtin_amdgcn_mfma_f32_16x16x32_bf16(aq[0][ks], bk, s[0][ni], 0, 0, 0);
        s[1][ni] = __builtin_amdgcn_mfma_f32_16x16x32_bf16(aq[1][ks], bk, s[1][ni], 0, 0, 0);
      }
    }
    __builtin_amdgcn_s_setprio(0);

    __builtin_amdgcn_s_barrier();
    __builtin_amdgcn_sched_barrier(0);
    if (j < qt) STAGE_K(j + 1);

    const bool diag = (j == qt);
#pragma unroll
    for (int mi = 0; mi < 2; ++mi) {
#pragma unroll
      for (int r = 0; r < 4; ++r) {
        int m = wave * 32 + mi * 16 + quad * 4 + r;
        float rmax = -1e30f;
#pragma unroll
        for (int ni = 0; ni < 8; ++ni) {
          float v = s[mi][ni][r] * cexp;
          if (diag && (ni * 16 + l16 > m)) v = -1e30f;
          s[mi][ni][r] = v;
          rmax = fmaxf(rmax, v);
        }
        rmax = fmaxf(rmax, __shfl_xor(rmax, 1));
        rmax = fmaxf(rmax, __shfl_xor(rmax, 2));
        rmax = fmaxf(rmax, __shfl_xor(rmax, 4));
        rmax = fmaxf(rmax, __shfl_xor(rmax, 8));
        float mnew = fmaxf(mrun[mi][r], rmax);
        float alpha = exp2f(mrun[mi][r] - mnew);
        mrun[mi][r] = mnew;
        float rsum = 0.f;
#pragma unroll
        for (int ni = 0; ni < 8; ++ni) {
          float pv = exp2f(s[mi][ni][r] - mnew);
          s[mi][ni][r] = pv;
          rsum += pv;
        }
        rsum += __shfl_xor(rsum, 1);
        rsum += __shfl_xor(rsum, 2);
        rsum += __shfl_xor(rsum, 4);
        rsum += __shfl_xor(rsum, 8);
        lrun[mi][r] = lrun[mi][r] * alpha + rsum;
#pragma unroll
        for (int di = 0; di < 4; ++di) o[mi][di][r] *= alpha;
      }
    }

    if (j < qt) { asm volatile("s_waitcnt vmcnt(4)" ::: "memory"); }
    else        { asm volatile("s_waitcnt vmcnt(0)" ::: "memory"); }
    __builtin_amdgcn_s_barrier();
    __builtin_amdgcn_sched_barrier(0);

#pragma unroll
    for (int mi = 0; mi < 2; ++mi) {
#pragma unroll
      for (int ni = 0; ni < 8; ++ni)
#pragma unroll
        for (int r = 0; r < 4; ++r) {
          int row = quad * 4 + r;
          int col = ni * 16 + l16;
          int phys = (col >> 3) ^ row;
          pw[row * 128 + phys * 8 + (col & 7)] = f2bf(s[mi][ni][r]);
        }

      __builtin_amdgcn_s_setprio(1);
#pragma unroll
      for (int ksv = 0; ksv < 4; ++ksv) {
        bf16x8 ap = *(const bf16x8*)(pw + l16 * 128 + (((ksv * 4 + quad) ^ l16) * 8));
#pragma unroll
        for (int di = 0; di < 4; ++di) {
          int n = di * 16 + l16;
          bf16x8 bv = *(const bf16x8*)(Vs + n * 128 + (((ksv * 4 + quad) ^ (n & 15)) * 8));
          o[mi][di] = __builtin_amdgcn_mfma_f32_16x16x32_bf16(ap, bv, o[mi][di], 0, 0, 0);
        }
      }
      __builtin_amdgcn_s_setprio(0);
    }

    asm volatile("s_waitcnt vmcnt(0)" ::: "memory");
    __builtin_amdgcn_s_barrier();
    __builtin_amdgcn_sched_barrier(0);
    if (j < qt) STAGE_V(j + 1);
  }
#undef STAGE_K
#undef STAGE_V

#pragma unroll
  for (int mi = 0; mi < 2; ++mi)
#pragma unroll
    for (int r = 0; r < 4; ++r) {
      float inv = 1.0f / lrun[mi][r];
      int trow = t0 + wave * 32 + mi * 16 + quad * 4 + r;
#pragma unroll
      for (int di = 0; di < 4; ++di)
        attn[(size_t)trow * 1024 + h * 64 + di * 16 + l16] = f2bf(o[mi][di][r] * inv);
    }
}

// ---------------------------------------------------------------------------
extern "C" void kernel_launch(void* const* d_in, const int* in_sizes, int n_in,
                              void* d_out, int out_size, void* d_ws, size_t ws_size,
                              hipStream_t stream) {
  (void)in_sizes; (void)n_in; (void)out_size; (void)ws_size;
  const float* x     = (const float*)d_in[0];   // [16384][1024] fp32
  const float* w_qkv = (const float*)d_in[1];   // [1024][3072] fp32
  const float* b_qkv = (const float*)d_in[2];   // [3072] fp32
  const float* w_o   = (const float*)d_in[3];   // [1024][1024] fp32
  const float* b_o   = (const float*)d_in[4];   // [1024] fp32
  float* out = (float*)d_out;                   // [16384][1024] fp32

  char* ws = (char*)d_ws;
  u16* qkv   = (u16*)(ws + 0);            // 96 MB
  u16* vtb   = (u16*)(ws + 100663296);    // 32 MB
  u16* attnb = (u16*)(ws + 134217728);    // 32 MB
  u16* xb    = (u16*)(ws + 167772160);    // 32 MB
  u16* wqkvT = (u16*)(ws + 201326592);    // 6 MB
  u16* woT   = (u16*)(ws + 207618048);    // 2 MB  (total 200 MB)

  canon_x<<<8192, 256, 0, stream>>>(x, xb);
  transpose_w<<<dim3(96, 32), 256, 0, stream>>>(w_qkv, wqkvT, 1024, 3072);
  transpose_w<<<dim3(32, 32), 256, 0, stream>>>(w_o, woT, 1024, 1024);

  gemm_bt_bias<u16><<<dim3(12, 64), 512, 0, stream>>>(
      xb, wqkvT, b_qkv, qkv, 16384, 3072, 1024);
  transpose_v<<<dim3(16, 2, 512), 256, 0, stream>>>(qkv, vtb);
  attn_win<<<dim3(4, 16, 32), 256, 0, stream>>>(qkv, vtb, attnb);
  gemm_bt_bias<float><<<dim3(4, 64), 512, 0, stream>>>(
      attnb, woT, b_o, out, 16384, 1024, 1024);
}

// Round 10
// 424.171 us; speedup vs baseline: 1.1033x; 1.0238x over previous
//
#include <hip/hip_runtime.h>

// Sliding-window attention, MI355X/gfx950. Round 15.
// Pipeline: prep_fused (x->bf16 + both weight transposes, one launch) ->
// m97 MFMA GEMM +T1 (qkv, bf16 out) -> V transpose -> flash windowed
// attention (R10 counted-vmcnt pipeline) -> m97 GEMM +T1 with FP32 epilogue.
// ws usage: 200 MB.
//
// LEDGER: R10 config = best measured total (427.8us; qkv gemm 139.8,
// WRITE 114MB, no spill). 256^2 GEMM attempts R11/R12/R13 = 452-468us,
// all with ~73-90MB scratch WRITE at the 2-wave/SIMD 256-reg boundary
// (acc128+bfr32+afr16 + transients). Decision rule fired: 256^2 is dead on
// this K=1024 shape; GEMMs reverted to R10-exact. R15 change: fuse the three
// independent prep kernels into one launch (7 -> 5 dispatches).

typedef unsigned short u16;
typedef unsigned int u32;
typedef __attribute__((ext_vector_type(8))) short bf16x8;   // 8 x bf16 (4 VGPRs)
typedef __attribute__((ext_vector_type(4))) float f32x4;

__device__ __forceinline__ float bf2f(u16 v) {
  union { u32 u; float f; } t; t.u = ((u32)v) << 16; return t.f;
}
__device__ __forceinline__ u16 f2bf(float f) {
  union { float f; u32 u; } t; t.f = f;
  u32 u = t.u + 0x7fffu + ((t.u >> 16) & 1u);   // RNE
  return (u16)(u >> 16);
}
__device__ __forceinline__ void g2lds16(const void* g, void* l) {
  __builtin_amdgcn_global_load_lds((const __attribute__((address_space(1))) void*)g,
                                   (__attribute__((address_space(3))) void*)l,
                                   16, 0, 0);
}

// ---------------------------------------------------------------------------
// Fused prep (one launch):
//   blocks [0, 8192):        x [16384][1024] fp32 -> bf16 flat
//   blocks [8192, 11264):    w_qkv [1024][3072] -> wqkvT [3072][1024] bf16
//   blocks [11264, 12288):   w_o   [1024][1024] -> woT   [1024][1024] bf16
// Per-block code identical to the three previously-verified kernels.
// ---------------------------------------------------------------------------
__global__ __launch_bounds__(256) void prep_fused(
    const float* __restrict__ xf, u16* __restrict__ xb,
    const float* __restrict__ wqkv, u16* __restrict__ wqkvT,
    const float* __restrict__ wo, u16* __restrict__ woT) {
  __shared__ u16 tile[32][33];
  const int b = blockIdx.x;
  if (b < 8192) {
    size_t i = ((size_t)b * 256 + threadIdx.x) * 8;
    float4 a = *(const float4*)(xf + i);
    float4 c = *(const float4*)(xf + i + 4);
    u16 o[8] = { f2bf(a.x), f2bf(a.y), f2bf(a.z), f2bf(a.w),
                 f2bf(c.x), f2bf(c.y), f2bf(c.z), f2bf(c.w) };
    *(bf16x8*)(xb + i) = *(bf16x8*)o;
    return;
  }
  const float* in;
  u16* out;
  int R = 1024, C, c0, r0;
  if (b < 11264) {
    int idx = b - 8192;                 // was grid (96, 32)
    in = wqkv; out = wqkvT; C = 3072;
    c0 = (idx % 96) * 32; r0 = (idx / 96) * 32;
  } else {
    int idx = b - 11264;                // was grid (32, 32)
    in = wo; out = woT; C = 1024;
    c0 = (idx % 32) * 32; r0 = (idx / 32) * 32;
  }
  int tx = threadIdx.x & 31, ty = threadIdx.x >> 5;
#pragma unroll
  for (int i = 0; i < 32; i += 8)
    tile[ty + i][tx] = f2bf(in[(size_t)(r0 + ty + i) * C + c0 + tx]);
  __syncthreads();
#pragma unroll
  for (int i = 0; i < 32; i += 8)
    out[(size_t)(c0 + ty + i) * R + r0 + tx] = tile[tx][ty + i];
}

// ---------------------------------------------------------------------------
// V part of qkv [16384][3072] -> Vt [bh=512][d=64][t=512]   (bf16)
// ---------------------------------------------------------------------------
__global__ __launch_bounds__(256) void transpose_v(
    const u16* __restrict__ qkv, u16* __restrict__ vt) {
  __shared__ u16 tile[32][33];
  int bh = blockIdx.z, bn = bh >> 4, h = bh & 15;
  int t0 = blockIdx.x * 32, d0 = blockIdx.y * 32;
  int tx = threadIdx.x & 31, ty = threadIdx.x >> 5;
  const u16* src = qkv + (size_t)(bn * 512) * 3072 + 2048 + h * 64;
#pragma unroll
  for (int i = 0; i < 32; i += 8)
    tile[ty + i][tx] = src[(size_t)(t0 + ty + i) * 3072 + d0 + tx];
  __syncthreads();
  u16* dst = vt + ((size_t)bh * 64 + d0) * 512 + t0;
#pragma unroll
  for (int i = 0; i < 32; i += 8)
    dst[(size_t)(ty + i) * 512 + tx] = tile[tx][ty + i];
}

// ---------------------------------------------------------------------------
// C[M,N] = A[M,K](bf16) * Bt[N,K]^T(bf16) + bias[N](fp32); OutT u16|float.
// m97 structure: 128x128 tile, BK=32, 2x2 waves of 64x64, global_load_lds
// w=16, T1 XCD swizzle (grid.x*grid.y % 8 == 0). R10-exact (verified).
// ---------------------------------------------------------------------------
template <typename OutT>
__global__ __launch_bounds__(256, 2) void gemm_bt_bias(
    const u16* __restrict__ A, const u16* __restrict__ Bt,
    const float* __restrict__ bias, OutT* __restrict__ C,
    int M, int N, int K) {
  __shared__ __align__(16) u16 As[128 * 32];
  __shared__ __align__(16) u16 Bs[128 * 32];
  const int tid = threadIdx.x;
  const int wave = tid >> 6, lane = tid & 63;
  const int quad = lane >> 4, l16 = lane & 15;

  // T1: dispatch index -> logical block, contiguous chunk per XCD.
  const int nbx = gridDim.x;
  const int ntot = nbx * gridDim.y;
  const int flat = blockIdx.y * nbx + blockIdx.x;
  const int swz = (flat & 7) * (ntot >> 3) + (flat >> 3);
  const int m0 = (swz / nbx) * 128, n0 = (swz % nbx) * 128;
  const int wm = (wave >> 1) * 64, wn = (wave & 1) * 64;

  f32x4 acc[4][4] = {};

  int e0 = (wave * 512) + lane * 8;   // chunk 0 element offset in 128x32 tile
  int e1 = 2048 + e0;                 // chunk 1
  int rA0 = e0 >> 5, cA0 = e0 & 31;
  int rA1 = e1 >> 5, cA1 = e1 & 31;
  const u16* ga0 = A + (size_t)(m0 + rA0) * K + cA0;
  const u16* ga1 = A + (size_t)(m0 + rA1) * K + cA1;
  const u16* gb0 = Bt + (size_t)(n0 + rA0) * K + cA0;
  const u16* gb1 = Bt + (size_t)(n0 + rA1) * K + cA1;
  u16* As0 = As + (size_t)wave * 512;
  u16* As1 = As0 + 2048;
  u16* Bs0 = Bs + (size_t)wave * 512;
  u16* Bs1 = Bs0 + 2048;

  for (int k0 = 0; k0 < K; k0 += 32) {
    g2lds16(ga0 + k0, As0);
    g2lds16(ga1 + k0, As1);
    g2lds16(gb0 + k0, Bs0);
    g2lds16(gb1 + k0, Bs1);
    __syncthreads();
    bf16x8 a[4], b[4];
#pragma unroll
    for (int mi = 0; mi < 4; ++mi)
      a[mi] = *(const bf16x8*)(As + (wm + mi * 16 + l16) * 32 + quad * 8);
#pragma unroll
    for (int ni = 0; ni < 4; ++ni)
      b[ni] = *(const bf16x8*)(Bs + (wn + ni * 16 + l16) * 32 + quad * 8);
#pragma unroll
    for (int mi = 0; mi < 4; ++mi)
#pragma unroll
      for (int ni = 0; ni < 4; ++ni)
        acc[mi][ni] = __builtin_amdgcn_mfma_f32_16x16x32_bf16(a[mi], b[ni], acc[mi][ni], 0, 0, 0);
    __syncthreads();
  }

  // epilogue: C/D layout col=l16, row=quad*4+reg
#pragma unroll
  for (int ni = 0; ni < 4; ++ni) {
    int col = n0 + wn + ni * 16 + l16;
    float bv = bias[col];
#pragma unroll
    for (int mi = 0; mi < 4; ++mi) {
      int row = m0 + wm + mi * 16 + quad * 4;
#pragma unroll
      for (int r = 0; r < 4; ++r) {
        float v = acc[mi][ni][r] + bv;
        if constexpr (sizeof(OutT) == 2)
          C[(size_t)(row + r) * N + col] = f2bf(v);
        else
          C[(size_t)(row + r) * N + col] = v;
      }
    }
  }
}

// ---------------------------------------------------------------------------
// Windowed causal flash attention. Grid (qt=4, h=16, bn=32), 256 threads.
// R10 (verified): counted-vmcnt pipeline, raw s_barrier, no __syncthreads.
//   barA (Ks free) -> DMA K(j+1) -> softmax -> vmcnt(4)/barD (V(j) landed)
//   -> P+PV -> vmcnt(0)/barB (Vs free, K(j+1) landed) -> DMA V(j+1).
// UNCHANGED.
// ---------------------------------------------------------------------------
__global__ __launch_bounds__(256, 2) void attn_win(
    const u16* __restrict__ qkv, const u16* __restrict__ vt,
    u16* __restrict__ attn) {
  __shared__ __align__(16) u16 Ks[128 * 64];
  __shared__ __align__(16) u16 Vs[64 * 128];
  __shared__ __align__(16) u16 Ps[4][16 * 128];

  const int qt = blockIdx.x, h = blockIdx.y, bn = blockIdx.z;
  const int bh = bn * 16 + h;
  const int tid = threadIdx.x;
  const int wave = tid >> 6, lane = tid & 63;
  const int quad = lane >> 4, l16 = lane & 15;
  const int t0 = bn * 512 + qt * 128;

  bf16x8 aq[2][2];
#pragma unroll
  for (int mi = 0; mi < 2; ++mi)
#pragma unroll
    for (int ks = 0; ks < 2; ++ks)
      aq[mi][ks] = *(const bf16x8*)(
          qkv + (size_t)(t0 + wave * 32 + mi * 16 + l16) * 3072 + h * 64 + ks * 32 + quad * 8);

  const int rk0 = tid >> 3, ck0 = tid & 7;
  const int rv0 = tid >> 4, cv0 = tid & 15;

#define STAGE_K(JT)                                                           \
  {                                                                           \
    const int tk_ = bn * 512 + (JT) * 128;                                    \
    _Pragma("unroll")                                                         \
    for (int it = 0; it < 4; ++it) {                                          \
      int rk = it * 32 + rk0;                                                 \
      const u16* gk = qkv + (size_t)(tk_ + rk) * 3072 + 1024 + h * 64 +       \
                      ((ck0 ^ (rk & 7)) * 8);                                 \
      g2lds16(gk, Ks + (size_t)(it * 256 + wave * 64) * 8);                   \
    }                                                                         \
  }
#define STAGE_V(JT)                                                           \
  {                                                                           \
    _Pragma("unroll")                                                         \
    for (int it = 0; it < 4; ++it) {                                          \
      int rv = it * 16 + rv0;                                                 \
      const u16* gv = vt + ((size_t)bh * 64 + rv) * 512 + (JT) * 128 +        \
                      ((cv0 ^ (rv & 15)) * 8);                                \
      g2lds16(gv, Vs + (size_t)(it * 256 + wave * 64) * 8);                   \
    }                                                                         \
  }

  STAGE_K(0);
  STAGE_V(0);
  asm volatile("s_waitcnt vmcnt(4)" ::: "memory");
  __builtin_amdgcn_s_barrier();
  __builtin_amdgcn_sched_barrier(0);

  float mrun[2][4], lrun[2][4];
  f32x4 o[2][4] = {};
#pragma unroll
  for (int mi = 0; mi < 2; ++mi)
#pragma unroll
    for (int r = 0; r < 4; ++r) { mrun[mi][r] = -1e30f; lrun[mi][r] = 0.f; }

  const float cexp = 0.18033688011112042f;  // (1/sqrt(64)) * log2(e)

  u16* pw = &Ps[wave][0];

  for (int j = 0; j <= qt; ++j) {
    f32x4 s[2][8] = {};
    __builtin_amdgcn_s_setprio(1);
#pragma unroll
    for (int ks = 0; ks < 2; ++ks) {
#pragma unroll
      for (int ni = 0; ni < 8; ++ni) {
        int n = ni * 16 + l16;
        bf16x8 bk = *(const bf16x8*)(Ks + n * 64 + (((ks * 4 + quad) ^ (n & 7)) * 8));
        s[0][ni] = __builtin_amdgcn_mfma_f32_16x16x32_bf16(aq[0][ks], bk, s[0][ni], 0, 0, 0);
        s[1][ni] = __builtin_amdgcn_mfma_f32_16x16x32_bf16(aq[1][ks], bk, s[1][ni], 0, 0, 0);
      }
    }
    __builtin_amdgcn_s_setprio(0);

    __builtin_amdgcn_s_barrier();
    __builtin_amdgcn_sched_barrier(0);
    if (j < qt) STAGE_K(j + 1);

    const bool diag = (j == qt);
#pragma unroll
    for (int mi = 0; mi < 2; ++mi) {
#pragma unroll
      for (int r = 0; r < 4; ++r) {
        int m = wave * 32 + mi * 16 + quad * 4 + r;
        float rmax = -1e30f;
#pragma unroll
        for (int ni = 0; ni < 8; ++ni) {
          float v = s[mi][ni][r] * cexp;
          if (diag && (ni * 16 + l16 > m)) v = -1e30f;
          s[mi][ni][r] = v;
          rmax = fmaxf(rmax, v);
        }
        rmax = fmaxf(rmax, __shfl_xor(rmax, 1));
        rmax = fmaxf(rmax, __shfl_xor(rmax, 2));
        rmax = fmaxf(rmax, __shfl_xor(rmax, 4));
        rmax = fmaxf(rmax, __shfl_xor(rmax, 8));
        float mnew = fmaxf(mrun[mi][r], rmax);
        float alpha = exp2f(mrun[mi][r] - mnew);
        mrun[mi][r] = mnew;
        float rsum = 0.f;
#pragma unroll
        for (int ni = 0; ni < 8; ++ni) {
          float pv = exp2f(s[mi][ni][r] - mnew);
          s[mi][ni][r] = pv;
          rsum += pv;
        }
        rsum += __shfl_xor(rsum, 1);
        rsum += __shfl_xor(rsum, 2);
        rsum += __shfl_xor(rsum, 4);
        rsum += __shfl_xor(rsum, 8);
        lrun[mi][r] = lrun[mi][r] * alpha + rsum;
#pragma unroll
        for (int di = 0; di < 4; ++di) o[mi][di][r] *= alpha;
      }
    }

    if (j < qt) { asm volatile("s_waitcnt vmcnt(4)" ::: "memory"); }
    else        { asm volatile("s_waitcnt vmcnt(0)" ::: "memory"); }
    __builtin_amdgcn_s_barrier();
    __builtin_amdgcn_sched_barrier(0);

#pragma unroll
    for (int mi = 0; mi < 2; ++mi) {
#pragma unroll
      for (int ni = 0; ni < 8; ++ni)
#pragma unroll
        for (int r = 0; r < 4; ++r) {
          int row = quad * 4 + r;
          int col = ni * 16 + l16;
          int phys = (col >> 3) ^ row;
          pw[row * 128 + phys * 8 + (col & 7)] = f2bf(s[mi][ni][r]);
        }

      __builtin_amdgcn_s_setprio(1);
#pragma unroll
      for (int ksv = 0; ksv < 4; ++ksv) {
        bf16x8 ap = *(const bf16x8*)(pw + l16 * 128 + (((ksv * 4 + quad) ^ l16) * 8));
#pragma unroll
        for (int di = 0; di < 4; ++di) {
          int n = di * 16 + l16;
          bf16x8 bv = *(const bf16x8*)(Vs + n * 128 + (((ksv * 4 + quad) ^ (n & 15)) * 8));
          o[mi][di] = __builtin_amdgcn_mfma_f32_16x16x32_bf16(ap, bv, o[mi][di], 0, 0, 0);
        }
      }
      __builtin_amdgcn_s_setprio(0);
    }

    asm volatile("s_waitcnt vmcnt(0)" ::: "memory");
    __builtin_amdgcn_s_barrier();
    __builtin_amdgcn_sched_barrier(0);
    if (j < qt) STAGE_V(j + 1);
  }
#undef STAGE_K
#undef STAGE_V

#pragma unroll
  for (int mi = 0; mi < 2; ++mi)
#pragma unroll
    for (int r = 0; r < 4; ++r) {
      float inv = 1.0f / lrun[mi][r];
      int trow = t0 + wave * 32 + mi * 16 + quad * 4 + r;
#pragma unroll
      for (int di = 0; di < 4; ++di)
        attn[(size_t)trow * 1024 + h * 64 + di * 16 + l16] = f2bf(o[mi][di][r] * inv);
    }
}

// ---------------------------------------------------------------------------
extern "C" void kernel_launch(void* const* d_in, const int* in_sizes, int n_in,
                              void* d_out, int out_size, void* d_ws, size_t ws_size,
                              hipStream_t stream) {
  (void)in_sizes; (void)n_in; (void)out_size; (void)ws_size;
  const float* x     = (const float*)d_in[0];   // [16384][1024] fp32
  const float* w_qkv = (const float*)d_in[1];   // [1024][3072] fp32
  const float* b_qkv = (const float*)d_in[2];   // [3072] fp32
  const float* w_o   = (const float*)d_in[3];   // [1024][1024] fp32
  const float* b_o   = (const float*)d_in[4];   // [1024] fp32
  float* out = (float*)d_out;                   // [16384][1024] fp32

  char* ws = (char*)d_ws;
  u16* qkv   = (u16*)(ws + 0);            // 96 MB
  u16* vtb   = (u16*)(ws + 100663296);    // 32 MB
  u16* attnb = (u16*)(ws + 134217728);    // 32 MB
  u16* xb    = (u16*)(ws + 167772160);    // 32 MB
  u16* wqkvT = (u16*)(ws + 201326592);    // 6 MB
  u16* woT   = (u16*)(ws + 207618048);    // 2 MB  (total 200 MB)

  prep_fused<<<12288, 256, 0, stream>>>(x, xb, w_qkv, wqkvT, w_o, woT);
  gemm_bt_bias<u16><<<dim3(24, 128), 256, 0, stream>>>(
      xb, wqkvT, b_qkv, qkv, 16384, 3072, 1024);
  transpose_v<<<dim3(16, 2, 512), 256, 0, stream>>>(qkv, vtb);
  attn_win<<<dim3(4, 16, 32), 256, 0, stream>>>(qkv, vtb, attnb);
  gemm_bt_bias<float><<<dim3(8, 128), 256, 0, stream>>>(
      attnb, woT, b_o, out, 16384, 1024, 1024);
}

// Round 11
// 411.148 us; speedup vs baseline: 1.1383x; 1.0317x over previous
//
#include <hip/hip_runtime.h>

// Sliding-window attention, MI355X/gfx950. Round 16.
// Pipeline: prep_fused -> m97 GEMM +T1 (qkv) -> V transpose -> flash
// windowed attention (R10 pipeline + R16 DPP softmax) -> m97 GEMM +T1 fp32.
//
// LEDGER: R15 = best (424.2us; qkv 136.5 no-spill; 5 launches). 256^2 GEMM
// dead on this shape (R11-R13: reg-file spill at 2-wave/SIMD boundary).
// R16 change (attn only, math-exact):
//  (a) 16-lane max-reduce via DPP butterfly (quad_perm 0xB1/0x4E,
//      row_half_mirror 0x141, row_mirror 0x140) - the reduce group (same
//      quad, l16=0..15) is exactly one DPP row. Replaces 32 ds_bpermute
//      shuffles/tile/lane with VALU ops.
//  (b) l (softmax denom) kept as PER-LANE PARTIAL (this lane's 8 cols),
//      updated lrun = lrun*alpha + partial per tile (alpha row-uniform);
//      single DPP add-reduce per row in the epilogue. Removes the other
//      32 shuffles/tile/lane. DS pipe now carries only P-writes + frag reads.

typedef unsigned short u16;
typedef unsigned int u32;
typedef __attribute__((ext_vector_type(8))) short bf16x8;   // 8 x bf16 (4 VGPRs)
typedef __attribute__((ext_vector_type(4))) float f32x4;

__device__ __forceinline__ float bf2f(u16 v) {
  union { u32 u; float f; } t; t.u = ((u32)v) << 16; return t.f;
}
__device__ __forceinline__ u16 f2bf(float f) {
  union { float f; u32 u; } t; t.f = f;
  u32 u = t.u + 0x7fffu + ((t.u >> 16) & 1u);   // RNE
  return (u16)(u >> 16);
}
__device__ __forceinline__ void g2lds16(const void* g, void* l) {
  __builtin_amdgcn_global_load_lds((const __attribute__((address_space(1))) void*)g,
                                   (__attribute__((address_space(3))) void*)l,
                                   16, 0, 0);
}

// 16-lane (one DPP row) butterfly reduce; all lanes end with the row result.
// Steps: xor1 (quad_perm [1,0,3,2]=0xB1), xor2 (quad_perm [2,3,0,1]=0x4E),
// cross-quad (row_half_mirror 0x141), cross-oct (row_mirror 0x140).
__device__ __forceinline__ float row16_max(float x) {
  union { float f; int i; } a, b;
  a.f = x; b.i = __builtin_amdgcn_update_dpp(0, a.i, 0xB1, 0xF, 0xF, false);
  x = fmaxf(x, b.f);
  a.f = x; b.i = __builtin_amdgcn_update_dpp(0, a.i, 0x4E, 0xF, 0xF, false);
  x = fmaxf(x, b.f);
  a.f = x; b.i = __builtin_amdgcn_update_dpp(0, a.i, 0x141, 0xF, 0xF, false);
  x = fmaxf(x, b.f);
  a.f = x; b.i = __builtin_amdgcn_update_dpp(0, a.i, 0x140, 0xF, 0xF, false);
  return fmaxf(x, b.f);
}
__device__ __forceinline__ float row16_sum(float x) {
  union { float f; int i; } a, b;
  a.f = x; b.i = __builtin_amdgcn_update_dpp(0, a.i, 0xB1, 0xF, 0xF, false);
  x += b.f;
  a.f = x; b.i = __builtin_amdgcn_update_dpp(0, a.i, 0x4E, 0xF, 0xF, false);
  x += b.f;
  a.f = x; b.i = __builtin_amdgcn_update_dpp(0, a.i, 0x141, 0xF, 0xF, false);
  x += b.f;
  a.f = x; b.i = __builtin_amdgcn_update_dpp(0, a.i, 0x140, 0xF, 0xF, false);
  return x + b.f;
}

// ---------------------------------------------------------------------------
// Fused prep (one launch):
//   blocks [0, 8192):        x [16384][1024] fp32 -> bf16 flat
//   blocks [8192, 11264):    w_qkv [1024][3072] -> wqkvT [3072][1024] bf16
//   blocks [11264, 12288):   w_o   [1024][1024] -> woT   [1024][1024] bf16
// ---------------------------------------------------------------------------
__global__ __launch_bounds__(256) void prep_fused(
    const float* __restrict__ xf, u16* __restrict__ xb,
    const float* __restrict__ wqkv, u16* __restrict__ wqkvT,
    const float* __restrict__ wo, u16* __restrict__ woT) {
  __shared__ u16 tile[32][33];
  const int b = blockIdx.x;
  if (b < 8192) {
    size_t i = ((size_t)b * 256 + threadIdx.x) * 8;
    float4 a = *(const float4*)(xf + i);
    float4 c = *(const float4*)(xf + i + 4);
    u16 o[8] = { f2bf(a.x), f2bf(a.y), f2bf(a.z), f2bf(a.w),
                 f2bf(c.x), f2bf(c.y), f2bf(c.z), f2bf(c.w) };
    *(bf16x8*)(xb + i) = *(bf16x8*)o;
    return;
  }
  const float* in;
  u16* out;
  int R = 1024, C, c0, r0;
  if (b < 11264) {
    int idx = b - 8192;                 // was grid (96, 32)
    in = wqkv; out = wqkvT; C = 3072;
    c0 = (idx % 96) * 32; r0 = (idx / 96) * 32;
  } else {
    int idx = b - 11264;                // was grid (32, 32)
    in = wo; out = woT; C = 1024;
    c0 = (idx % 32) * 32; r0 = (idx / 32) * 32;
  }
  int tx = threadIdx.x & 31, ty = threadIdx.x >> 5;
#pragma unroll
  for (int i = 0; i < 32; i += 8)
    tile[ty + i][tx] = f2bf(in[(size_t)(r0 + ty + i) * C + c0 + tx]);
  __syncthreads();
#pragma unroll
  for (int i = 0; i < 32; i += 8)
    out[(size_t)(c0 + ty + i) * R + r0 + tx] = tile[tx][ty + i];
}

// ---------------------------------------------------------------------------
// V part of qkv [16384][3072] -> Vt [bh=512][d=64][t=512]   (bf16)
// ---------------------------------------------------------------------------
__global__ __launch_bounds__(256) void transpose_v(
    const u16* __restrict__ qkv, u16* __restrict__ vt) {
  __shared__ u16 tile[32][33];
  int bh = blockIdx.z, bn = bh >> 4, h = bh & 15;
  int t0 = blockIdx.x * 32, d0 = blockIdx.y * 32;
  int tx = threadIdx.x & 31, ty = threadIdx.x >> 5;
  const u16* src = qkv + (size_t)(bn * 512) * 3072 + 2048 + h * 64;
#pragma unroll
  for (int i = 0; i < 32; i += 8)
    tile[ty + i][tx] = src[(size_t)(t0 + ty + i) * 3072 + d0 + tx];
  __syncthreads();
  u16* dst = vt + ((size_t)bh * 64 + d0) * 512 + t0;
#pragma unroll
  for (int i = 0; i < 32; i += 8)
    dst[(size_t)(ty + i) * 512 + tx] = tile[tx][ty + i];
}

// ---------------------------------------------------------------------------
// C[M,N] = A[M,K](bf16) * Bt[N,K]^T(bf16) + bias[N](fp32); OutT u16|float.
// m97 structure: 128x128 tile, BK=32, 2x2 waves of 64x64, global_load_lds
// w=16, T1 XCD swizzle (grid.x*grid.y % 8 == 0). R10/R15-exact (verified).
// ---------------------------------------------------------------------------
template <typename OutT>
__global__ __launch_bounds__(256, 2) void gemm_bt_bias(
    const u16* __restrict__ A, const u16* __restrict__ Bt,
    const float* __restrict__ bias, OutT* __restrict__ C,
    int M, int N, int K) {
  __shared__ __align__(16) u16 As[128 * 32];
  __shared__ __align__(16) u16 Bs[128 * 32];
  const int tid = threadIdx.x;
  const int wave = tid >> 6, lane = tid & 63;
  const int quad = lane >> 4, l16 = lane & 15;

  // T1: dispatch index -> logical block, contiguous chunk per XCD.
  const int nbx = gridDim.x;
  const int ntot = nbx * gridDim.y;
  const int flat = blockIdx.y * nbx + blockIdx.x;
  const int swz = (flat & 7) * (ntot >> 3) + (flat >> 3);
  const int m0 = (swz / nbx) * 128, n0 = (swz % nbx) * 128;
  const int wm = (wave >> 1) * 64, wn = (wave & 1) * 64;

  f32x4 acc[4][4] = {};

  int e0 = (wave * 512) + lane * 8;   // chunk 0 element offset in 128x32 tile
  int e1 = 2048 + e0;                 // chunk 1
  int rA0 = e0 >> 5, cA0 = e0 & 31;
  int rA1 = e1 >> 5, cA1 = e1 & 31;
  const u16* ga0 = A + (size_t)(m0 + rA0) * K + cA0;
  const u16* ga1 = A + (size_t)(m0 + rA1) * K + cA1;
  const u16* gb0 = Bt + (size_t)(n0 + rA0) * K + cA0;
  const u16* gb1 = Bt + (size_t)(n0 + rA1) * K + cA1;
  u16* As0 = As + (size_t)wave * 512;
  u16* As1 = As0 + 2048;
  u16* Bs0 = Bs + (size_t)wave * 512;
  u16* Bs1 = Bs0 + 2048;

  for (int k0 = 0; k0 < K; k0 += 32) {
    g2lds16(ga0 + k0, As0);
    g2lds16(ga1 + k0, As1);
    g2lds16(gb0 + k0, Bs0);
    g2lds16(gb1 + k0, Bs1);
    __syncthreads();
    bf16x8 a[4], b[4];
#pragma unroll
    for (int mi = 0; mi < 4; ++mi)
      a[mi] = *(const bf16x8*)(As + (wm + mi * 16 + l16) * 32 + quad * 8);
#pragma unroll
    for (int ni = 0; ni < 4; ++ni)
      b[ni] = *(const bf16x8*)(Bs + (wn + ni * 16 + l16) * 32 + quad * 8);
#pragma unroll
    for (int mi = 0; mi < 4; ++mi)
#pragma unroll
      for (int ni = 0; ni < 4; ++ni)
        acc[mi][ni] = __builtin_amdgcn_mfma_f32_16x16x32_bf16(a[mi], b[ni], acc[mi][ni], 0, 0, 0);
    __syncthreads();
  }

  // epilogue: C/D layout col=l16, row=quad*4+reg
#pragma unroll
  for (int ni = 0; ni < 4; ++ni) {
    int col = n0 + wn + ni * 16 + l16;
    float bv = bias[col];
#pragma unroll
    for (int mi = 0; mi < 4; ++mi) {
      int row = m0 + wm + mi * 16 + quad * 4;
#pragma unroll
      for (int r = 0; r < 4; ++r) {
        float v = acc[mi][ni][r] + bv;
        if constexpr (sizeof(OutT) == 2)
          C[(size_t)(row + r) * N + col] = f2bf(v);
        else
          C[(size_t)(row + r) * N + col] = v;
      }
    }
  }
}

// ---------------------------------------------------------------------------
// Windowed causal flash attention. Grid (qt=4, h=16, bn=32), 256 threads.
// R10 counted-vmcnt pipeline (verified) + R16 DPP softmax:
//  - max-reduce over the row's 16 lanes via DPP butterfly (no ds_bpermute)
//  - l kept per-lane partial; one DPP sum-reduce per row in the epilogue.
// ---------------------------------------------------------------------------
__global__ __launch_bounds__(256, 2) void attn_win(
    const u16* __restrict__ qkv, const u16* __restrict__ vt,
    u16* __restrict__ attn) {
  __shared__ __align__(16) u16 Ks[128 * 64];
  __shared__ __align__(16) u16 Vs[64 * 128];
  __shared__ __align__(16) u16 Ps[4][16 * 128];

  const int qt = blockIdx.x, h = blockIdx.y, bn = blockIdx.z;
  const int bh = bn * 16 + h;
  const int tid = threadIdx.x;
  const int wave = tid >> 6, lane = tid & 63;
  const int quad = lane >> 4, l16 = lane & 15;
  const int t0 = bn * 512 + qt * 128;

  bf16x8 aq[2][2];
#pragma unroll
  for (int mi = 0; mi < 2; ++mi)
#pragma unroll
    for (int ks = 0; ks < 2; ++ks)
      aq[mi][ks] = *(const bf16x8*)(
          qkv + (size_t)(t0 + wave * 32 + mi * 16 + l16) * 3072 + h * 64 + ks * 32 + quad * 8);

  const int rk0 = tid >> 3, ck0 = tid & 7;
  const int rv0 = tid >> 4, cv0 = tid & 15;

#define STAGE_K(JT)                                                           \
  {                                                                           \
    const int tk_ = bn * 512 + (JT) * 128;                                    \
    _Pragma("unroll")                                                         \
    for (int it = 0; it < 4; ++it) {                                          \
      int rk = it * 32 + rk0;                                                 \
      const u16* gk = qkv + (size_t)(tk_ + rk) * 3072 + 1024 + h * 64 +       \
                      ((ck0 ^ (rk & 7)) * 8);                                 \
      g2lds16(gk, Ks + (size_t)(it * 256 + wave * 64) * 8);                   \
    }                                                                         \
  }
#define STAGE_V(JT)                                                           \
  {                                                                           \
    _Pragma("unroll")                                                         \
    for (int it = 0; it < 4; ++it) {                                          \
      int rv = it * 16 + rv0;                                                 \
      const u16* gv = vt + ((size_t)bh * 64 + rv) * 512 + (JT) * 128 +        \
                      ((cv0 ^ (rv & 15)) * 8);                                \
      g2lds16(gv, Vs + (size_t)(it * 256 + wave * 64) * 8);                   \
    }                                                                         \
  }

  STAGE_K(0);
  STAGE_V(0);
  asm volatile("s_waitcnt vmcnt(4)" ::: "memory");
  __builtin_amdgcn_s_barrier();
  __builtin_amdgcn_sched_barrier(0);

  float mrun[2][4], lrun[2][4];        // lrun = per-lane PARTIAL sums (R16)
  f32x4 o[2][4] = {};
#pragma unroll
  for (int mi = 0; mi < 2; ++mi)
#pragma unroll
    for (int r = 0; r < 4; ++r) { mrun[mi][r] = -1e30f; lrun[mi][r] = 0.f; }

  const float cexp = 0.18033688011112042f;  // (1/sqrt(64)) * log2(e)

  u16* pw = &Ps[wave][0];

  for (int j = 0; j <= qt; ++j) {
    f32x4 s[2][8] = {};
    __builtin_amdgcn_s_setprio(1);
#pragma unroll
    for (int ks = 0; ks < 2; ++ks) {
#pragma unroll
      for (int ni = 0; ni < 8; ++ni) {
        int n = ni * 16 + l16;
        bf16x8 bk = *(const bf16x8*)(Ks + n * 64 + (((ks * 4 + quad) ^ (n & 7)) * 8));
        s[0][ni] = __builtin_amdgcn_mfma_f32_16x16x32_bf16(aq[0][ks], bk, s[0][ni], 0, 0, 0);
        s[1][ni] = __builtin_amdgcn_mfma_f32_16x16x32_bf16(aq[1][ks], bk, s[1][ni], 0, 0, 0);
      }
    }
    __builtin_amdgcn_s_setprio(0);

    __builtin_amdgcn_s_barrier();
    __builtin_amdgcn_sched_barrier(0);
    if (j < qt) STAGE_K(j + 1);

    // ---- online softmax (C layout: col=l16, row=quad*4+r) ----
    const bool diag = (j == qt);
#pragma unroll
    for (int mi = 0; mi < 2; ++mi) {
#pragma unroll
      for (int r = 0; r < 4; ++r) {
        int m = wave * 32 + mi * 16 + quad * 4 + r;
        float rmax = -1e30f;
#pragma unroll
        for (int ni = 0; ni < 8; ++ni) {
          float v = s[mi][ni][r] * cexp;
          if (diag && (ni * 16 + l16 > m)) v = -1e30f;
          s[mi][ni][r] = v;
          rmax = fmaxf(rmax, v);
        }
        rmax = row16_max(rmax);                    // DPP butterfly (R16)
        float mnew = fmaxf(mrun[mi][r], rmax);
        float alpha = exp2f(mrun[mi][r] - mnew);
        mrun[mi][r] = mnew;
        float rsum = 0.f;
#pragma unroll
        for (int ni = 0; ni < 8; ++ni) {
          float pv = exp2f(s[mi][ni][r] - mnew);
          s[mi][ni][r] = pv;
          rsum += pv;
        }
        lrun[mi][r] = lrun[mi][r] * alpha + rsum;  // partial (no reduce)
#pragma unroll
        for (int di = 0; di < 4; ++di) o[mi][di][r] *= alpha;
      }
    }

    if (j < qt) { asm volatile("s_waitcnt vmcnt(4)" ::: "memory"); }
    else        { asm volatile("s_waitcnt vmcnt(0)" ::: "memory"); }
    __builtin_amdgcn_s_barrier();
    __builtin_amdgcn_sched_barrier(0);

#pragma unroll
    for (int mi = 0; mi < 2; ++mi) {
#pragma unroll
      for (int ni = 0; ni < 8; ++ni)
#pragma unroll
        for (int r = 0; r < 4; ++r) {
          int row = quad * 4 + r;
          int col = ni * 16 + l16;
          int phys = (col >> 3) ^ row;
          pw[row * 128 + phys * 8 + (col & 7)] = f2bf(s[mi][ni][r]);
        }

      __builtin_amdgcn_s_setprio(1);
#pragma unroll
      for (int ksv = 0; ksv < 4; ++ksv) {
        bf16x8 ap = *(const bf16x8*)(pw + l16 * 128 + (((ksv * 4 + quad) ^ l16) * 8));
#pragma unroll
        for (int di = 0; di < 4; ++di) {
          int n = di * 16 + l16;
          bf16x8 bv = *(const bf16x8*)(Vs + n * 128 + (((ksv * 4 + quad) ^ (n & 15)) * 8));
          o[mi][di] = __builtin_amdgcn_mfma_f32_16x16x32_bf16(ap, bv, o[mi][di], 0, 0, 0);
        }
      }
      __builtin_amdgcn_s_setprio(0);
    }

    asm volatile("s_waitcnt vmcnt(0)" ::: "memory");
    __builtin_amdgcn_s_barrier();
    __builtin_amdgcn_sched_barrier(0);
    if (j < qt) STAGE_V(j + 1);
  }
#undef STAGE_K
#undef STAGE_V

  // ---- epilogue: reduce l partials once, then O / l -> attn (bf16) ----
#pragma unroll
  for (int mi = 0; mi < 2; ++mi)
#pragma unroll
    for (int r = 0; r < 4; ++r) {
      float inv = 1.0f / row16_sum(lrun[mi][r]);   // DPP reduce (R16)
      int trow = t0 + wave * 32 + mi * 16 + quad * 4 + r;
#pragma unroll
      for (int di = 0; di < 4; ++di)
        attn[(size_t)trow * 1024 + h * 64 + di * 16 + l16] = f2bf(o[mi][di][r] * inv);
    }
}

// ---------------------------------------------------------------------------
extern "C" void kernel_launch(void* const* d_in, const int* in_sizes, int n_in,
                              void* d_out, int out_size, void* d_ws, size_t ws_size,
                              hipStream_t stream) {
  (void)in_sizes; (void)n_in; (void)out_size; (void)ws_size;
  const float* x     = (const float*)d_in[0];   // [16384][1024] fp32
  const float* w_qkv = (const float*)d_in[1];   // [1024][3072] fp32
  const float* b_qkv = (const float*)d_in[2];   // [3072] fp32
  const float* w_o   = (const float*)d_in[3];   // [1024][1024] fp32
  const float* b_o   = (const float*)d_in[4];   // [1024] fp32
  float* out = (float*)d_out;                   // [16384][1024] fp32

  char* ws = (char*)d_ws;
  u16* qkv   = (u16*)(ws + 0);            // 96 MB
  u16* vtb   = (u16*)(ws + 100663296);    // 32 MB
  u16* attnb = (u16*)(ws + 134217728);    // 32 MB
  u16* xb    = (u16*)(ws + 167772160);    // 32 MB
  u16* wqkvT = (u16*)(ws + 201326592);    // 6 MB
  u16* woT   = (u16*)(ws + 207618048);    // 2 MB  (total 200 MB)

  prep_fused<<<12288, 256, 0, stream>>>(x, xb, w_qkv, wqkvT, w_o, woT);
  gemm_bt_bias<u16><<<dim3(24, 128), 256, 0, stream>>>(
      xb, wqkvT, b_qkv, qkv, 16384, 3072, 1024);
  transpose_v<<<dim3(16, 2, 512), 256, 0, stream>>>(qkv, vtb);
  attn_win<<<dim3(4, 16, 32), 256, 0, stream>>>(qkv, vtb, attnb);
  gemm_bt_bias<float><<<dim3(8, 128), 256, 0, stream>>>(
      attnb, woT, b_o, out, 16384, 1024, 1024);
}